// Round 10
// baseline (18981.041 us; speedup 1.0000x reference)
//
#include <hip/hip_runtime.h>
#include <hip/hip_cooperative_groups.h>
#include <math.h>

#define BB 64   // batch
#define TT 64   // time steps
#define NN 512  // nodes
#define HH 32   // hidden
#define CC 33   // C_IN + H
#define EE 10   // embed dim
#define GG 128  // 4*H
#define COLS 2112 // B*H + B
#define AZS (NN * COLS)
#define KS 4
#define NJOBS (33 * 8 * KS)  // j-tiles x n-tiles x splitK = 1056

namespace cg = cooperative_groups;

// ---------------- prologue kernels (proven) ----------------

__global__ __launch_bounds__(256) void k_A(const float* __restrict__ E,
                                           const float* __restrict__ mask,
                                           float* __restrict__ A) {
  __shared__ float sE[NN * EE];
  __shared__ float red[256];
  int tid = threadIdx.x, n = blockIdx.x;
  for (int i = tid; i < NN * EE; i += 256) sE[i] = E[i];
  __syncthreads();
  float en[EE];
#pragma unroll
  for (int d = 0; d < EE; ++d) en[d] = sE[n * EE + d];
  float sv[2];
  float mx = -1e30f;
#pragma unroll
  for (int r = 0; r < 2; ++r) {
    int m = tid + r * 256;
    float s = 0.f;
#pragma unroll
    for (int d = 0; d < EE; ++d) s += en[d] * sE[m * EE + d];
    s = fmaxf(s, 0.f);
    sv[r] = s;
    mx = fmaxf(mx, s);
  }
  red[tid] = mx; __syncthreads();
  for (int s = 128; s > 0; s >>= 1) {
    if (tid < s) red[tid] = fmaxf(red[tid], red[tid + s]);
    __syncthreads();
  }
  mx = red[0]; __syncthreads();
  float sum = 0.f;
#pragma unroll
  for (int r = 0; r < 2; ++r) { sv[r] = expf(sv[r] - mx); sum += sv[r]; }
  red[tid] = sum; __syncthreads();
  for (int s = 128; s > 0; s >>= 1) {
    if (tid < s) red[tid] += red[tid + s];
    __syncthreads();
  }
  float inv = 1.f / red[0];
#pragma unroll
  for (int r = 0; r < 2; ++r) {
    int m = tid + r * 256;
    A[n * NN + m] = sv[r] * inv * mask[n * NN + m];
  }
}

__global__ __launch_bounds__(256) void k_Wb(const float* __restrict__ E,
                                            const float* __restrict__ Wp,
                                            const float* __restrict__ bp,
                                            float* __restrict__ W,
                                            float* __restrict__ bias) {
  int tid = threadIdx.x, n = blockIdx.x;
  float e[EE];
#pragma unroll
  for (int d = 0; d < EE; ++d) e[d] = E[n * EE + d];
  for (int i = tid; i < 2 * CC * GG; i += 256) {
    float acc = 0.f;
#pragma unroll
    for (int d = 0; d < EE; ++d) acc += e[d] * Wp[d * (2 * CC * GG) + i];
    W[n * (2 * CC * GG) + i] = acc;
  }
  if (tid < GG) {
    float acc = 0.f;
#pragma unroll
    for (int d = 0; d < EE; ++d) acc += e[d] * bp[d * GG + tid];
    bias[n * GG + tid] = acc;
  }
}

__global__ __launch_bounds__(256) void k_xt(const float* __restrict__ x,
                                            float* __restrict__ xt) {
  __shared__ float tile[64][65];
  int tid = threadIdx.x;
  int t = blockIdx.x >> 3, m0 = (blockIdx.x & 7) << 6;
  int l16 = tid & 15, grp = tid >> 4;
#pragma unroll
  for (int r = 0; r < 4; ++r) {
    int b = r * 16 + grp;
    float4 v = *reinterpret_cast<const float4*>(&x[(b * TT + t) * NN + m0 + l16 * 4]);
    tile[b][l16 * 4 + 0] = v.x; tile[b][l16 * 4 + 1] = v.y;
    tile[b][l16 * 4 + 2] = v.z; tile[b][l16 * 4 + 3] = v.w;
  }
  __syncthreads();
#pragma unroll
  for (int r = 0; r < 4; ++r) {
    int m = r * 16 + grp;
    float4 v;
    v.x = tile[l16 * 4 + 0][m]; v.y = tile[l16 * 4 + 1][m];
    v.z = tile[l16 * 4 + 2][m]; v.w = tile[l16 * 4 + 3][m];
    *reinterpret_cast<float4*>(&xt[(t * NN + m0 + m) * BB + l16 * 4]) = v;
  }
}

__global__ __launch_bounds__(256) void k_init(const float* __restrict__ init,
                                              float* __restrict__ h,
                                              float* __restrict__ c) {
  int i = blockIdx.x * 256 + threadIdx.x;
  if (i >= NN * BB * HH) return;
  int n = i >> 11, r = i & 2047, b = r >> 5, hh = r & 31;
  h[i] = init[((b * 2 + 0) * NN + n) * HH + hh];
  c[i] = init[((b * 2 + 1) * NN + n) * HH + hh];
}

// ---------------- fallback per-step kernels (round-8, proven) ----------------

__global__ __launch_bounds__(256) void k_gemm(const float* __restrict__ A,
                                              const float* __restrict__ h,
                                              const float* __restrict__ xt,
                                              float* __restrict__ azp,
                                              int t, int ks) {
  __shared__ float As[32][68];
  __shared__ float Bs[32][64];
  int tid = threadIdx.x;
  int j0 = blockIdx.x * 64;
  int n0 = blockIdx.y * 64;
  int kz = blockIdx.z;
  int Klen = NN / ks;
  int kbase = kz * Klen;
  int tx = tid & 15, ty = tid >> 4;
  int arow = tid >> 2;
  int akc = (tid & 3) * 4;
  int bcol4 = tid & 15;
  int brow0 = tid >> 4;
  const bool xtile = (j0 >= BB * HH);
  float acc[4][4] = {};
  for (int k0 = kbase; k0 < kbase + Klen; k0 += 32) {
    float4 a0 = *reinterpret_cast<const float4*>(&A[(n0 + arow) * NN + k0 + akc]);
    float4 a1 = *reinterpret_cast<const float4*>(&A[(n0 + arow) * NN + k0 + 16 + akc]);
    As[akc + 0][arow] = a0.x; As[akc + 1][arow] = a0.y;
    As[akc + 2][arow] = a0.z; As[akc + 3][arow] = a0.w;
    As[16 + akc + 0][arow] = a1.x; As[16 + akc + 1][arow] = a1.y;
    As[16 + akc + 2][arow] = a1.z; As[16 + akc + 3][arow] = a1.w;
#pragma unroll
    for (int p = 0; p < 2; ++p) {
      int brow = brow0 + p * 16;
      float4 b4;
      if (!xtile)
        b4 = *reinterpret_cast<const float4*>(&h[(k0 + brow) * (BB * HH) + j0 + bcol4 * 4]);
      else
        b4 = *reinterpret_cast<const float4*>(&xt[(t * NN + k0 + brow) * BB + (j0 - BB * HH) + bcol4 * 4]);
      *reinterpret_cast<float4*>(&Bs[brow][bcol4 * 4]) = b4;
    }
    __syncthreads();
#pragma unroll
    for (int kk = 0; kk < 32; ++kk) {
      float4 av = *reinterpret_cast<const float4*>(&As[kk][ty * 4]);
      float4 bv = *reinterpret_cast<const float4*>(&Bs[kk][tx * 4]);
      float a[4] = {av.x, av.y, av.z, av.w};
      float b[4] = {bv.x, bv.y, bv.z, bv.w};
#pragma unroll
      for (int i = 0; i < 4; ++i)
#pragma unroll
        for (int j = 0; j < 4; ++j) acc[i][j] += a[i] * b[j];
    }
    __syncthreads();
  }
  float* dst = azp + (size_t)kz * AZS;
#pragma unroll
  for (int i = 0; i < 4; ++i) {
    float4 v = {acc[i][0], acc[i][1], acc[i][2], acc[i][3]};
    *reinterpret_cast<float4*>(&dst[(n0 + ty * 4 + i) * COLS + j0 + tx * 4]) = v;
  }
}

__global__ __launch_bounds__(256) void k_step(const float* __restrict__ xt,
                                              const float* __restrict__ W,
                                              const float* __restrict__ bias,
                                              const float* __restrict__ azp,
                                              float* __restrict__ h,
                                              float* __restrict__ c,
                                              float* __restrict__ out,
                                              int t, int ks) {
  __shared__ float Wl[2 * CC * GG];
  __shared__ float zl[2 * CC * 68];
  int tid = threadIdx.x, n = blockIdx.x;
  const float4* Wg = reinterpret_cast<const float4*>(&W[n * (2 * CC * GG)]);
  for (int i = tid; i < (2 * CC * GG) / 4; i += 256)
    *reinterpret_cast<float4*>(&Wl[i * 4]) = Wg[i];
  for (int i = tid; i < BB * HH; i += 256) {
    int b = i >> 5, hh = i & 31;
    zl[(1 + hh) * 68 + b] = h[n * (BB * HH) + i];
    float s = azp[n * COLS + i];
    for (int kz = 1; kz < ks; ++kz) s += azp[(size_t)kz * AZS + n * COLS + i];
    zl[(CC + 1 + hh) * 68 + b] = s;
  }
  if (tid < BB) {
    zl[0 * 68 + tid] = xt[(t * NN + n) * BB + tid];
    float s = azp[n * COLS + BB * HH + tid];
    for (int kz = 1; kz < ks; ++kz) s += azp[(size_t)kz * AZS + n * COLS + BB * HH + tid];
    zl[CC * 68 + tid] = s;
  }
  __syncthreads();
  int tx = tid & 31, tyb = tid >> 5;
  float acc[8][4];
  {
    float4 bv = *reinterpret_cast<const float4*>(&bias[n * GG + tx * 4]);
#pragma unroll
    for (int bb = 0; bb < 8; ++bb) {
      acc[bb][0] = bv.x; acc[bb][1] = bv.y; acc[bb][2] = bv.z; acc[bb][3] = bv.w;
    }
  }
  for (int k = 0; k < 2; ++k) {
    for (int cc = 0; cc < CC; ++cc) {
      float4 w4 = *reinterpret_cast<const float4*>(&Wl[(k * CC + cc) * GG + tx * 4]);
      float4 za = *reinterpret_cast<const float4*>(&zl[(k * CC + cc) * 68 + tyb * 8]);
      float4 zb = *reinterpret_cast<const float4*>(&zl[(k * CC + cc) * 68 + tyb * 8 + 4]);
      float zv[8] = {za.x, za.y, za.z, za.w, zb.x, zb.y, zb.z, zb.w};
      float wv[4] = {w4.x, w4.y, w4.z, w4.w};
#pragma unroll
      for (int bb = 0; bb < 8; ++bb)
#pragma unroll
        for (int j = 0; j < 4; ++j) acc[bb][j] += zv[bb] * wv[j];
    }
  }
  __syncthreads();
  float* gl = Wl;
#pragma unroll
  for (int bb = 0; bb < 8; ++bb) {
    float4 v = {acc[bb][0], acc[bb][1], acc[bb][2], acc[bb][3]};
    *reinterpret_cast<float4*>(&gl[(tyb * 8 + bb) * GG + tx * 4]) = v;
  }
  __syncthreads();
  for (int i = tid; i < BB * HH; i += 256) {
    int b = i >> 5, hh = i & 31;
    float gi = gl[b * GG + hh];
    float gf = gl[b * GG + 32 + hh];
    float go = gl[b * GG + 64 + hh];
    float gg = gl[b * GG + 96 + hh];
    float cold = c[n * (BB * HH) + i];
    float si = 1.f / (1.f + expf(-gi));
    float sf = 1.f / (1.f + expf(-gf));
    float so = 1.f / (1.f + expf(-go));
    float cnew = sf * cold + si * tanhf(gg);
    float hnew = so * tanhf(cnew);
    c[n * (BB * HH) + i] = cnew;
    h[n * (BB * HH) + i] = hnew;
    out[((b * TT + t) * NN + n) * HH + hh] = hnew;
  }
}

// ---------------- cooperative whole-recurrence kernel ----------------
// 512 blocks x 256 threads. LDS = 17.95 KB (union of phase-A tiles / phase-B zl).
// Phase A: round-8 k_gemm body over the 1056-job space (same fp order).
// Phase B: node n = bid; gates from W in global (wave-broadcast), same fp order.
__global__ __launch_bounds__(256, 2) void k_loop(
    const float* __restrict__ A, float* __restrict__ h,
    const float* __restrict__ xt, const float* __restrict__ W,
    const float* __restrict__ bias, float* __restrict__ c,
    float* __restrict__ azp, float* __restrict__ out) {
  cg::grid_group grid = cg::this_grid();
  __shared__ float smem[4488];  // max(As 2176 + Bs 2048, zl 4488)
  float (*As)[68] = reinterpret_cast<float (*)[68]>(smem);
  float (*Bs)[64] = reinterpret_cast<float (*)[64]>(smem + 2176);
  float* zl = smem;
  const int tid = threadIdx.x;
  const int bid = blockIdx.x;
  // phase-A ids (round-8 mappings)
  const int tx = tid & 15, ty = tid >> 4;
  const int arow = tid >> 2, akc = (tid & 3) * 4;
  const int brow0 = tid >> 4, bcol4 = tid & 15;
  // phase-B ids: thread owns (batch bb, hiddens oh*8..+7, all 4 gates)
  const int bb = tid >> 2, oh = tid & 3;
  const int n = bid;
  const float* Wn = W + n * (2 * CC * GG);
  // bias preload (once)
  float bs[4][8];
#pragma unroll
  for (int g = 0; g < 4; ++g) {
    float4 b0 = *reinterpret_cast<const float4*>(&bias[n * GG + g * 32 + oh * 8]);
    float4 b1 = *reinterpret_cast<const float4*>(&bias[n * GG + g * 32 + oh * 8 + 4]);
    bs[g][0] = b0.x; bs[g][1] = b0.y; bs[g][2] = b0.z; bs[g][3] = b0.w;
    bs[g][4] = b1.x; bs[g][5] = b1.y; bs[g][6] = b1.z; bs[g][7] = b1.w;
  }

  for (int t = 0; t < TT; ++t) {
    // ---------- phase A: az partials ----------
    for (int job = bid; job < NJOBS; job += 512) {
      int kz = job & (KS - 1);
      int rem = job >> 2;          // 0..263
      int jc = rem % 33, nr = rem / 33;
      int j0 = jc * 64, n0 = nr * 64;
      int kbase = kz * (NN / KS);
      const bool xtile = (jc == 32);
      float acc[4][4] = {};
      for (int k0 = kbase; k0 < kbase + NN / KS; k0 += 32) {
        float4 a0 = *reinterpret_cast<const float4*>(&A[(n0 + arow) * NN + k0 + akc]);
        float4 a1 = *reinterpret_cast<const float4*>(&A[(n0 + arow) * NN + k0 + 16 + akc]);
        As[akc + 0][arow] = a0.x; As[akc + 1][arow] = a0.y;
        As[akc + 2][arow] = a0.z; As[akc + 3][arow] = a0.w;
        As[16 + akc + 0][arow] = a1.x; As[16 + akc + 1][arow] = a1.y;
        As[16 + akc + 2][arow] = a1.z; As[16 + akc + 3][arow] = a1.w;
#pragma unroll
        for (int p = 0; p < 2; ++p) {
          int brow = brow0 + p * 16;
          float4 b4;
          if (!xtile)
            b4 = *reinterpret_cast<const float4*>(&h[(k0 + brow) * (BB * HH) + j0 + bcol4 * 4]);
          else
            b4 = *reinterpret_cast<const float4*>(&xt[(t * NN + k0 + brow) * BB + bcol4 * 4]);
          *reinterpret_cast<float4*>(&Bs[brow][bcol4 * 4]) = b4;
        }
        __syncthreads();
#pragma unroll
        for (int kk = 0; kk < 32; ++kk) {
          float4 av = *reinterpret_cast<const float4*>(&As[kk][ty * 4]);
          float4 bw = *reinterpret_cast<const float4*>(&Bs[kk][tx * 4]);
          float a[4] = {av.x, av.y, av.z, av.w};
          float b[4] = {bw.x, bw.y, bw.z, bw.w};
#pragma unroll
          for (int i = 0; i < 4; ++i)
#pragma unroll
            for (int j = 0; j < 4; ++j) acc[i][j] += a[i] * b[j];
        }
        __syncthreads();
      }
      float* dst = azp + (size_t)kz * AZS;
#pragma unroll
      for (int i = 0; i < 4; ++i) {
        float4 v = {acc[i][0], acc[i][1], acc[i][2], acc[i][3]};
        *reinterpret_cast<float4*>(&dst[(n0 + ty * 4 + i) * COLS + j0 + tx * 4]) = v;
      }
    }
    __threadfence();
    grid.sync();

    // ---------- phase B: gates + LSTM update for node n ----------
    for (int i = tid; i < BB * HH; i += 256) {
      int b = i >> 5, hh = i & 31;
      zl[(1 + hh) * 68 + b] = h[n * (BB * HH) + i];
      float s = azp[n * COLS + i];
#pragma unroll
      for (int kz = 1; kz < KS; ++kz) s += azp[(size_t)kz * AZS + n * COLS + i];
      zl[(CC + 1 + hh) * 68 + b] = s;
    }
    if (tid < BB) {
      zl[0 * 68 + tid] = xt[(t * NN + n) * BB + tid];
      float s = azp[n * COLS + BB * HH + tid];
#pragma unroll
      for (int kz = 1; kz < KS; ++kz) s += azp[(size_t)kz * AZS + n * COLS + BB * HH + tid];
      zl[CC * 68 + tid] = s;
    }
    __syncthreads();
    float acc[4][8];
#pragma unroll
    for (int g = 0; g < 4; ++g)
#pragma unroll
      for (int q = 0; q < 8; ++q) acc[g][q] = bs[g][q];
    for (int r = 0; r < 2 * CC; ++r) {
      float z = zl[r * 68 + bb];
      const float* wr = Wn + r * GG;
#pragma unroll
      for (int g = 0; g < 4; ++g) {
        float4 w0 = *reinterpret_cast<const float4*>(&wr[g * 32 + oh * 8]);
        float4 w1 = *reinterpret_cast<const float4*>(&wr[g * 32 + oh * 8 + 4]);
        acc[g][0] += z * w0.x; acc[g][1] += z * w0.y;
        acc[g][2] += z * w0.z; acc[g][3] += z * w0.w;
        acc[g][4] += z * w1.x; acc[g][5] += z * w1.y;
        acc[g][6] += z * w1.z; acc[g][7] += z * w1.w;
      }
    }
    int io = n * (BB * HH) + bb * HH + oh * 8;
    float4 c0 = *reinterpret_cast<const float4*>(&c[io]);
    float4 c1 = *reinterpret_cast<const float4*>(&c[io + 4]);
    float cn[8], hn[8];
#pragma unroll
    for (int q = 0; q < 8; ++q) {
      float cold = (q < 4) ? (&c0.x)[q] : (&c1.x)[q - 4];
      float si = 1.f / (1.f + expf(-acc[0][q]));
      float sf = 1.f / (1.f + expf(-acc[1][q]));
      float so = 1.f / (1.f + expf(-acc[2][q]));
      float cc2 = sf * cold + si * tanhf(acc[3][q]);
      cn[q] = cc2;
      hn[q] = so * tanhf(cc2);
    }
    float4 v0 = {cn[0], cn[1], cn[2], cn[3]}, v1 = {cn[4], cn[5], cn[6], cn[7]};
    *reinterpret_cast<float4*>(&c[io]) = v0;
    *reinterpret_cast<float4*>(&c[io + 4]) = v1;
    float4 u0 = {hn[0], hn[1], hn[2], hn[3]}, u1 = {hn[4], hn[5], hn[6], hn[7]};
    *reinterpret_cast<float4*>(&h[io]) = u0;
    *reinterpret_cast<float4*>(&h[io + 4]) = u1;
    size_t oo = ((size_t)(bb * TT + t) * NN + n) * HH + oh * 8;
    *reinterpret_cast<float4*>(&out[oo]) = u0;
    *reinterpret_cast<float4*>(&out[oo + 4]) = u1;
    __threadfence();
    grid.sync();
  }
}

extern "C" void kernel_launch(void* const* d_in, const int* in_sizes, int n_in,
                              void* d_out, int out_size, void* d_ws, size_t ws_size,
                              hipStream_t stream) {
  const float* x    = (const float*)d_in[0];
  const float* init = (const float*)d_in[1];
  const float* E    = (const float*)d_in[2];
  const float* mask = (const float*)d_in[3];
  const float* Wp   = (const float*)d_in[4];
  const float* bp   = (const float*)d_in[5];
  float* out = (float*)d_out;
  float* ws = (float*)d_ws;
  float* A    = ws;
  float* W    = A + NN * NN;
  float* bias = W + NN * 2 * CC * GG;
  float* xt   = bias + NN * GG;
  float* h    = xt + TT * NN * BB;
  float* c    = h + NN * BB * HH;
  float* azp  = c + NN * BB * HH;  // KS slices

  k_A<<<NN, 256, 0, stream>>>(E, mask, A);
  k_Wb<<<NN, 256, 0, stream>>>(E, Wp, bp, W, bias);
  k_xt<<<TT * 8, 256, 0, stream>>>(x, xt);
  k_init<<<(NN * BB * HH + 255) / 256, 256, 0, stream>>>(init, h, c);

  void* args[8] = {(void*)&A, (void*)&h, (void*)&xt, (void*)&W,
                   (void*)&bias, (void*)&c, (void*)&azp, (void*)&out};
  hipError_t err = hipLaunchCooperativeKernel((const void*)k_loop, dim3(512),
                                              dim3(256), args, 0, stream);
  if (err != hipSuccess) {
    // fallback: proven round-8 two-kernel loop
    for (int t = 0; t < TT; ++t) {
      k_gemm<<<dim3(33, 8, KS), 256, 0, stream>>>(A, h, xt, azp, t, KS);
      k_step<<<NN, 256, 0, stream>>>(xt, W, bias, azp, h, c, out, t, KS);
    }
  }
}

// Round 11
// 6370.484 us; speedup vs baseline: 2.9795x; 2.9795x over previous
//
#include <hip/hip_runtime.h>
#include <math.h>

#define BB 64   // batch
#define TT 64   // time steps
#define NN 512  // nodes
#define HH 32   // hidden
#define CC 33   // C_IN + H
#define EE 10   // embed dim
#define GG 128  // 4*H

// ---------------- prologue kernels (proven) ----------------

__global__ __launch_bounds__(256) void k_A(const float* __restrict__ E,
                                           const float* __restrict__ mask,
                                           float* __restrict__ A) {
  __shared__ float sE[NN * EE];
  __shared__ float red[256];
  int tid = threadIdx.x, n = blockIdx.x;
  for (int i = tid; i < NN * EE; i += 256) sE[i] = E[i];
  __syncthreads();
  float en[EE];
#pragma unroll
  for (int d = 0; d < EE; ++d) en[d] = sE[n * EE + d];
  float sv[2];
  float mx = -1e30f;
#pragma unroll
  for (int r = 0; r < 2; ++r) {
    int m = tid + r * 256;
    float s = 0.f;
#pragma unroll
    for (int d = 0; d < EE; ++d) s += en[d] * sE[m * EE + d];
    s = fmaxf(s, 0.f);
    sv[r] = s;
    mx = fmaxf(mx, s);
  }
  red[tid] = mx; __syncthreads();
  for (int s = 128; s > 0; s >>= 1) {
    if (tid < s) red[tid] = fmaxf(red[tid], red[tid + s]);
    __syncthreads();
  }
  mx = red[0]; __syncthreads();
  float sum = 0.f;
#pragma unroll
  for (int r = 0; r < 2; ++r) { sv[r] = expf(sv[r] - mx); sum += sv[r]; }
  red[tid] = sum; __syncthreads();
  for (int s = 128; s > 0; s >>= 1) {
    if (tid < s) red[tid] += red[tid + s];
    __syncthreads();
  }
  float inv = 1.f / red[0];
#pragma unroll
  for (int r = 0; r < 2; ++r) {
    int m = tid + r * 256;
    A[n * NN + m] = sv[r] * inv * mask[n * NN + m];
  }
}

__global__ __launch_bounds__(256) void k_Wb(const float* __restrict__ E,
                                            const float* __restrict__ Wp,
                                            const float* __restrict__ bp,
                                            float* __restrict__ W,
                                            float* __restrict__ bias) {
  int tid = threadIdx.x, n = blockIdx.x;
  float e[EE];
#pragma unroll
  for (int d = 0; d < EE; ++d) e[d] = E[n * EE + d];
  for (int i = tid; i < 2 * CC * GG; i += 256) {
    float acc = 0.f;
#pragma unroll
    for (int d = 0; d < EE; ++d) acc += e[d] * Wp[d * (2 * CC * GG) + i];
    W[n * (2 * CC * GG) + i] = acc;
  }
  if (tid < GG) {
    float acc = 0.f;
#pragma unroll
    for (int d = 0; d < EE; ++d) acc += e[d] * bp[d * GG + tid];
    bias[n * GG + tid] = acc;
  }
}

__global__ __launch_bounds__(256) void k_xt(const float* __restrict__ x,
                                            float* __restrict__ xt) {
  __shared__ float tile[64][65];
  int tid = threadIdx.x;
  int t = blockIdx.x >> 3, m0 = (blockIdx.x & 7) << 6;
  int l16 = tid & 15, grp = tid >> 4;
#pragma unroll
  for (int r = 0; r < 4; ++r) {
    int b = r * 16 + grp;
    float4 v = *reinterpret_cast<const float4*>(&x[(b * TT + t) * NN + m0 + l16 * 4]);
    tile[b][l16 * 4 + 0] = v.x; tile[b][l16 * 4 + 1] = v.y;
    tile[b][l16 * 4 + 2] = v.z; tile[b][l16 * 4 + 3] = v.w;
  }
  __syncthreads();
#pragma unroll
  for (int r = 0; r < 4; ++r) {
    int m = r * 16 + grp;
    float4 v;
    v.x = tile[l16 * 4 + 0][m]; v.y = tile[l16 * 4 + 1][m];
    v.z = tile[l16 * 4 + 2][m]; v.w = tile[l16 * 4 + 3][m];
    *reinterpret_cast<float4*>(&xt[(t * NN + m0 + m) * BB + l16 * 4]) = v;
  }
}

__global__ __launch_bounds__(256) void k_init(const float* __restrict__ init,
                                              float* __restrict__ h,
                                              float* __restrict__ c) {
  int i = blockIdx.x * 256 + threadIdx.x;
  if (i >= NN * BB * HH) return;
  int n = i >> 11, r = i & 2047, b = r >> 5, hh = r & 31;
  h[i] = init[((b * 2 + 0) * NN + n) * HH + hh];
  c[i] = init[((b * 2 + 1) * NN + n) * HH + hh];
}

// ---------------- fused per-step kernel ----------------
// Block = 16 nodes x 8 batches. Grid (32, 8) = 256 blocks. 256 threads.
// Phase 1: az tile (16 x 256 h-cols + 16 x 8 x-cols), K=512, LDS-tiled.
// Phase 2: gates + LSTM update for the block's 128 (n,b) pairs.
// h double-buffered across launches (hcur read, hnxt written).
__global__ __launch_bounds__(256) void k_fstep(
    const float* __restrict__ A, const float* __restrict__ hcur,
    float* __restrict__ hnxt, const float* __restrict__ xt,
    const float* __restrict__ W, const float* __restrict__ bias,
    float* __restrict__ c, float* __restrict__ out, int t) {
  __shared__ float As[16][17];      // [kr][n]
  __shared__ float Bs[16][260];     // [kr][col]; reused as azs[16 n][256] after
  __shared__ float Bx[16][8];       // [kr][b] x-cheb operand
  __shared__ float azx[16][8];
  __shared__ float hloc[16][260];   // h identity term [n][b*32+hh]
  __shared__ float xloc[16][8];
  __shared__ float gl[16][8][132];  // gates [n][b][o]
  const int tid = threadIdx.x;
  const int n0 = blockIdx.x * 16;
  const int bb0 = blockIdx.y * 8;
  const int hc0 = bb0 * 32;  // h column base
  // phase-1 ids
  const int ty = tid >> 4, tx = tid & 15;   // compute: n-row ty, col-quads tx
  const int sr = tid >> 4, sf4 = tid & 15;  // staging row / float4-col
  const int xn = tid >> 3, xb = tid & 7;    // tid<128: azx roles

  float acc[4][4] = {};
  float ax = 0.f;
  for (int k0 = 0; k0 < NN; k0 += 16) {
    {
      int n = tid >> 4, kr = tid & 15;
      As[kr][n] = A[(n0 + n) * NN + k0 + kr];
    }
#pragma unroll
    for (int p = 0; p < 4; ++p) {
      int c4 = sf4 + p * 16;
      float4 v = *reinterpret_cast<const float4*>(
          &hcur[(k0 + sr) * 2048 + hc0 + c4 * 4]);
      *reinterpret_cast<float4*>(&Bs[sr][c4 * 4]) = v;
    }
    if (tid < 128)
      Bx[xn][xb] = xt[(t * NN + k0 + xn) * BB + bb0 + xb];
    __syncthreads();
#pragma unroll
    for (int kk = 0; kk < 16; ++kk) {
      float a = As[kk][ty];
      float4 b0 = *reinterpret_cast<const float4*>(&Bs[kk][tx * 4]);
      float4 b1 = *reinterpret_cast<const float4*>(&Bs[kk][tx * 4 + 64]);
      float4 b2 = *reinterpret_cast<const float4*>(&Bs[kk][tx * 4 + 128]);
      float4 b3 = *reinterpret_cast<const float4*>(&Bs[kk][tx * 4 + 192]);
      acc[0][0] += a * b0.x; acc[0][1] += a * b0.y;
      acc[0][2] += a * b0.z; acc[0][3] += a * b0.w;
      acc[1][0] += a * b1.x; acc[1][1] += a * b1.y;
      acc[1][2] += a * b1.z; acc[1][3] += a * b1.w;
      acc[2][0] += a * b2.x; acc[2][1] += a * b2.y;
      acc[2][2] += a * b2.z; acc[2][3] += a * b2.w;
      acc[3][0] += a * b3.x; acc[3][1] += a * b3.y;
      acc[3][2] += a * b3.z; acc[3][3] += a * b3.w;
      if (tid < 128) ax += As[kk][xn] * Bx[kk][xb];
    }
    __syncthreads();
  }
  // write az tile into Bs region (safe: last barrier drained all Bs reads)
#pragma unroll
  for (int p = 0; p < 4; ++p) {
    float4 v = {acc[p][0], acc[p][1], acc[p][2], acc[p][3]};
    *reinterpret_cast<float4*>(&Bs[ty][tx * 4 + p * 64]) = v;
  }
  if (tid < 128) azx[xn][xb] = ax;
  // stage identity terms
#pragma unroll
  for (int p = 0; p < 4; ++p) {
    int c4 = sf4 + p * 16;
    float4 v = *reinterpret_cast<const float4*>(
        &hcur[(n0 + sr) * 2048 + hc0 + c4 * 4]);
    *reinterpret_cast<float4*>(&hloc[sr][c4 * 4]) = v;
  }
  if (tid < 128)
    xloc[xn][xb] = xt[(t * NN + n0 + xn) * BB + bb0 + xb];
  __syncthreads();

  // ---------- phase 2: gates ----------
  const int gn = tid >> 4, oq = tid & 15;  // node-row, o-oct (8 outputs)
  const float* Wn = W + (size_t)(n0 + gn) * (2 * CC * GG);
  float g2[8][8];
  {
    float4 b0 = *reinterpret_cast<const float4*>(&bias[(n0 + gn) * GG + oq * 8]);
    float4 b1 = *reinterpret_cast<const float4*>(&bias[(n0 + gn) * GG + oq * 8 + 4]);
#pragma unroll
    for (int b = 0; b < 8; ++b) {
      g2[b][0] = b0.x; g2[b][1] = b0.y; g2[b][2] = b0.z; g2[b][3] = b0.w;
      g2[b][4] = b1.x; g2[b][5] = b1.y; g2[b][6] = b1.z; g2[b][7] = b1.w;
    }
  }
  for (int cc = 0; cc < 2 * CC; ++cc) {
    int k1 = (cc >= CC);
    int c2 = cc - (k1 ? CC : 0);
    float zv[8];
    if (c2 == 0) {
#pragma unroll
      for (int b = 0; b < 8; ++b) zv[b] = k1 ? azx[gn][b] : xloc[gn][b];
    } else {
      int hh2 = c2 - 1;
#pragma unroll
      for (int b = 0; b < 8; ++b)
        zv[b] = k1 ? Bs[gn][b * 32 + hh2] : hloc[gn][b * 32 + hh2];
    }
    float4 w0 = *reinterpret_cast<const float4*>(&Wn[cc * GG + oq * 8]);
    float4 w1 = *reinterpret_cast<const float4*>(&Wn[cc * GG + oq * 8 + 4]);
#pragma unroll
    for (int b = 0; b < 8; ++b) {
      g2[b][0] += zv[b] * w0.x; g2[b][1] += zv[b] * w0.y;
      g2[b][2] += zv[b] * w0.z; g2[b][3] += zv[b] * w0.w;
      g2[b][4] += zv[b] * w1.x; g2[b][5] += zv[b] * w1.y;
      g2[b][6] += zv[b] * w1.z; g2[b][7] += zv[b] * w1.w;
    }
  }
#pragma unroll
  for (int b = 0; b < 8; ++b) {
    float4 v0 = {g2[b][0], g2[b][1], g2[b][2], g2[b][3]};
    float4 v1 = {g2[b][4], g2[b][5], g2[b][6], g2[b][7]};
    *reinterpret_cast<float4*>(&gl[gn][b][oq * 8]) = v0;
    *reinterpret_cast<float4*>(&gl[gn][b][oq * 8 + 4]) = v1;
  }
  __syncthreads();

  // ---------- LSTM update ----------
  const int ub = tid >> 5, uhh = tid & 31;  // batch-local, hidden
#pragma unroll 4
  for (int v = 0; v < 16; ++v) {
    float gi = gl[v][ub][uhh];
    float gf = gl[v][ub][32 + uhh];
    float go = gl[v][ub][64 + uhh];
    float gg = gl[v][ub][96 + uhh];
    int io = (n0 + v) * 2048 + hc0 + ub * 32 + uhh;
    float cold = c[io];
    float si = 1.f / (1.f + expf(-gi));
    float sf = 1.f / (1.f + expf(-gf));
    float so = 1.f / (1.f + expf(-go));
    float cn = sf * cold + si * tanhf(gg);
    float hn = so * tanhf(cn);
    c[io] = cn;
    hnxt[io] = hn;
    out[((size_t)((bb0 + ub) * TT + t) * NN + (n0 + v)) * HH + uhh] = hn;
  }
}

extern "C" void kernel_launch(void* const* d_in, const int* in_sizes, int n_in,
                              void* d_out, int out_size, void* d_ws, size_t ws_size,
                              hipStream_t stream) {
  const float* x    = (const float*)d_in[0];
  const float* init = (const float*)d_in[1];
  const float* E    = (const float*)d_in[2];
  const float* mask = (const float*)d_in[3];
  const float* Wp   = (const float*)d_in[4];
  const float* bp   = (const float*)d_in[5];
  float* out = (float*)d_out;
  float* ws = (float*)d_ws;
  float* A    = ws;
  float* W    = A + NN * NN;
  float* bias = W + NN * 2 * CC * GG;
  float* xt   = bias + NN * GG;
  float* h0   = xt + TT * NN * BB;
  float* h1   = h0 + NN * BB * HH;
  float* c    = h1 + NN * BB * HH;

  k_A<<<NN, 256, 0, stream>>>(E, mask, A);
  k_Wb<<<NN, 256, 0, stream>>>(E, Wp, bp, W, bias);
  k_xt<<<TT * 8, 256, 0, stream>>>(x, xt);
  k_init<<<(NN * BB * HH + 255) / 256, 256, 0, stream>>>(init, h0, c);

  for (int t = 0; t < TT; ++t) {
    float* hcur = (t & 1) ? h1 : h0;
    float* hnxt = (t & 1) ? h0 : h1;
    k_fstep<<<dim3(32, 8), 256, 0, stream>>>(A, hcur, hnxt, xt, W, bias, c, out, t);
  }
}

// Round 13
// 3536.975 us; speedup vs baseline: 5.3665x; 1.8011x over previous
//
#include <hip/hip_runtime.h>
#include <hip/hip_cooperative_groups.h>
#include <math.h>

#define BB 64   // batch
#define TT 64   // time steps
#define NN 512  // nodes
#define HH 32   // hidden
#define CC 33   // C_IN + H
#define EE 10   // embed dim
#define GG 128  // 4*H
#define COLS 2112
#define AZS (NN * COLS)
#define KS 4
#define NB 512  // persistent blocks

// Coherent (cross-XCD) access: relaxed agent-scope atomics compile to plain
// loads/stores with sc1 -> serviced at the chip-coherent point (LLC).
__device__ __forceinline__ float cload(const float* p) {
  return __hip_atomic_load(p, __ATOMIC_RELAXED, __HIP_MEMORY_SCOPE_AGENT);
}
__device__ __forceinline__ void cstore(float* p, float v) {
  __hip_atomic_store(p, v, __ATOMIC_RELAXED, __HIP_MEMORY_SCOPE_AGENT);
}

// Hierarchical grid barrier: 8 group counters (128B apart) + release flag.
// __syncthreads drains vmcnt (sc1 stores acked at LLC) before arrival.
__device__ __forceinline__ void gbar(unsigned* bar, unsigned epoch, int bid) {
  __syncthreads();
  if (threadIdx.x == 0) {
    unsigned g = (unsigned)bid >> 6;
    __hip_atomic_fetch_add(&bar[g * 32], 1u, __ATOMIC_RELAXED,
                           __HIP_MEMORY_SCOPE_AGENT);
    if (bid == 0) {
      for (int gg = 0; gg < 8; ++gg)
        while (__hip_atomic_load(&bar[gg * 32], __ATOMIC_RELAXED,
                                 __HIP_MEMORY_SCOPE_AGENT) < 64u * epoch)
          __builtin_amdgcn_s_sleep(4);
      __hip_atomic_store(&bar[256], epoch, __ATOMIC_RELAXED,
                         __HIP_MEMORY_SCOPE_AGENT);
    } else {
      while (__hip_atomic_load(&bar[256], __ATOMIC_RELAXED,
                               __HIP_MEMORY_SCOPE_AGENT) < epoch)
        __builtin_amdgcn_s_sleep(4);
    }
  }
  __syncthreads();
}

// ---------------- prologue kernels ----------------

__global__ __launch_bounds__(256) void k_A(const float* __restrict__ E,
                                           const float* __restrict__ mask,
                                           float* __restrict__ A) {
  __shared__ float sE[NN * EE];
  __shared__ float red[256];
  int tid = threadIdx.x, n = blockIdx.x;
  for (int i = tid; i < NN * EE; i += 256) sE[i] = E[i];
  __syncthreads();
  float en[EE];
#pragma unroll
  for (int d = 0; d < EE; ++d) en[d] = sE[n * EE + d];
  float sv[2];
  float mx = -1e30f;
#pragma unroll
  for (int r = 0; r < 2; ++r) {
    int m = tid + r * 256;
    float s = 0.f;
#pragma unroll
    for (int d = 0; d < EE; ++d) s += en[d] * sE[m * EE + d];
    s = fmaxf(s, 0.f);
    sv[r] = s;
    mx = fmaxf(mx, s);
  }
  red[tid] = mx; __syncthreads();
  for (int s = 128; s > 0; s >>= 1) {
    if (tid < s) red[tid] = fmaxf(red[tid], red[tid + s]);
    __syncthreads();
  }
  mx = red[0]; __syncthreads();
  float sum = 0.f;
#pragma unroll
  for (int r = 0; r < 2; ++r) { sv[r] = expf(sv[r] - mx); sum += sv[r]; }
  red[tid] = sum; __syncthreads();
  for (int s = 128; s > 0; s >>= 1) {
    if (tid < s) red[tid] += red[tid + s];
    __syncthreads();
  }
  float inv = 1.f / red[0];
#pragma unroll
  for (int r = 0; r < 2; ++r) {
    int m = tid + r * 256;
    A[n * NN + m] = sv[r] * inv * mask[n * NN + m];
  }
}

__global__ __launch_bounds__(256) void k_Wb(const float* __restrict__ E,
                                            const float* __restrict__ Wp,
                                            const float* __restrict__ bp,
                                            float* __restrict__ W,
                                            float* __restrict__ bias) {
  int tid = threadIdx.x, n = blockIdx.x;
  float e[EE];
#pragma unroll
  for (int d = 0; d < EE; ++d) e[d] = E[n * EE + d];
  for (int i = tid; i < 2 * CC * GG; i += 256) {
    float acc = 0.f;
#pragma unroll
    for (int d = 0; d < EE; ++d) acc += e[d] * Wp[d * (2 * CC * GG) + i];
    W[n * (2 * CC * GG) + i] = acc;
  }
  if (tid < GG) {
    float acc = 0.f;
#pragma unroll
    for (int d = 0; d < EE; ++d) acc += e[d] * bp[d * GG + tid];
    bias[n * GG + tid] = acc;
  }
}

__global__ __launch_bounds__(256) void k_xt(const float* __restrict__ x,
                                            float* __restrict__ xt) {
  __shared__ float tile[64][65];
  int tid = threadIdx.x;
  int t = blockIdx.x >> 3, m0 = (blockIdx.x & 7) << 6;
  int l16 = tid & 15, grp = tid >> 4;
#pragma unroll
  for (int r = 0; r < 4; ++r) {
    int b = r * 16 + grp;
    float4 v = *reinterpret_cast<const float4*>(&x[(b * TT + t) * NN + m0 + l16 * 4]);
    tile[b][l16 * 4 + 0] = v.x; tile[b][l16 * 4 + 1] = v.y;
    tile[b][l16 * 4 + 2] = v.z; tile[b][l16 * 4 + 3] = v.w;
  }
  __syncthreads();
#pragma unroll
  for (int r = 0; r < 4; ++r) {
    int m = r * 16 + grp;
    float4 v;
    v.x = tile[l16 * 4 + 0][m]; v.y = tile[l16 * 4 + 1][m];
    v.z = tile[l16 * 4 + 2][m]; v.w = tile[l16 * 4 + 3][m];
    *reinterpret_cast<float4*>(&xt[(t * NN + m0 + m) * BB + l16 * 4]) = v;
  }
}

// ax[t][n][b] = sum_m A[n][m] * xt[t][m][b]
__global__ __launch_bounds__(256) void k_ax(const float* __restrict__ A,
                                            const float* __restrict__ xt,
                                            float* __restrict__ ax) {
  __shared__ float As[32][68];
  __shared__ float Bs[32][64];
  int tid = threadIdx.x;
  int t = blockIdx.x;
  int n0 = blockIdx.y * 64;
  int tx = tid & 15, ty = tid >> 4;
  int arow = tid >> 2, akc = (tid & 3) * 4;
  int bcol4 = tid & 15, brow0 = tid >> 4;
  float acc[4][4] = {};
  for (int k0 = 0; k0 < NN; k0 += 32) {
    float4 a0 = *reinterpret_cast<const float4*>(&A[(n0 + arow) * NN + k0 + akc]);
    float4 a1 = *reinterpret_cast<const float4*>(&A[(n0 + arow) * NN + k0 + 16 + akc]);
    As[akc + 0][arow] = a0.x; As[akc + 1][arow] = a0.y;
    As[akc + 2][arow] = a0.z; As[akc + 3][arow] = a0.w;
    As[16 + akc + 0][arow] = a1.x; As[16 + akc + 1][arow] = a1.y;
    As[16 + akc + 2][arow] = a1.z; As[16 + akc + 3][arow] = a1.w;
#pragma unroll
    for (int p = 0; p < 2; ++p) {
      int brow = brow0 + p * 16;
      float4 b4 = *reinterpret_cast<const float4*>(&xt[(t * NN + k0 + brow) * BB + bcol4 * 4]);
      *reinterpret_cast<float4*>(&Bs[brow][bcol4 * 4]) = b4;
    }
    __syncthreads();
#pragma unroll
    for (int kk = 0; kk < 32; ++kk) {
      float4 av = *reinterpret_cast<const float4*>(&As[kk][ty * 4]);
      float4 bv = *reinterpret_cast<const float4*>(&Bs[kk][tx * 4]);
      float a[4] = {av.x, av.y, av.z, av.w};
      float b[4] = {bv.x, bv.y, bv.z, bv.w};
#pragma unroll
      for (int i = 0; i < 4; ++i)
#pragma unroll
        for (int j = 0; j < 4; ++j) acc[i][j] += a[i] * b[j];
    }
    __syncthreads();
  }
#pragma unroll
  for (int i = 0; i < 4; ++i) {
    float4 v = {acc[i][0], acc[i][1], acc[i][2], acc[i][3]};
    *reinterpret_cast<float4*>(&ax[(size_t)(t * NN + n0 + ty * 4 + i) * BB + tx * 4]) = v;
  }
}

// h/c init; zero the barrier area (agent-scope so k_persist sees it fresh).
__global__ __launch_bounds__(256) void k_init(const float* __restrict__ init,
                                              float* __restrict__ h,
                                              float* __restrict__ c,
                                              unsigned* __restrict__ bar) {
  int i = blockIdx.x * 256 + threadIdx.x;
  if (i < 257)
    __hip_atomic_store(&bar[i], 0u, __ATOMIC_RELAXED, __HIP_MEMORY_SCOPE_AGENT);
  if (i >= NN * BB * HH) return;
  int n = i >> 11, r = i & 2047, b = r >> 5, hh = r & 31;
  h[i] = init[((b * 2 + 0) * NN + n) * HH + hh];
  c[i] = init[((b * 2 + 1) * NN + n) * HH + hh];
}

// ---------------- fallback per-step kernels (round-8, proven) ----------------

__global__ __launch_bounds__(256) void k_gemm(const float* __restrict__ A,
                                              const float* __restrict__ h,
                                              const float* __restrict__ xt,
                                              float* __restrict__ azp,
                                              int t, int ks) {
  __shared__ float As[32][68];
  __shared__ float Bs[32][64];
  int tid = threadIdx.x;
  int j0 = blockIdx.x * 64;
  int n0 = blockIdx.y * 64;
  int kz = blockIdx.z;
  int Klen = NN / ks;
  int kbase = kz * Klen;
  int tx = tid & 15, ty = tid >> 4;
  int arow = tid >> 2;
  int akc = (tid & 3) * 4;
  int bcol4 = tid & 15;
  int brow0 = tid >> 4;
  const bool xtile = (j0 >= BB * HH);
  float acc[4][4] = {};
  for (int k0 = kbase; k0 < kbase + Klen; k0 += 32) {
    float4 a0 = *reinterpret_cast<const float4*>(&A[(n0 + arow) * NN + k0 + akc]);
    float4 a1 = *reinterpret_cast<const float4*>(&A[(n0 + arow) * NN + k0 + 16 + akc]);
    As[akc + 0][arow] = a0.x; As[akc + 1][arow] = a0.y;
    As[akc + 2][arow] = a0.z; As[akc + 3][arow] = a0.w;
    As[16 + akc + 0][arow] = a1.x; As[16 + akc + 1][arow] = a1.y;
    As[16 + akc + 2][arow] = a1.z; As[16 + akc + 3][arow] = a1.w;
#pragma unroll
    for (int p = 0; p < 2; ++p) {
      int brow = brow0 + p * 16;
      float4 b4;
      if (!xtile)
        b4 = *reinterpret_cast<const float4*>(&h[(k0 + brow) * (BB * HH) + j0 + bcol4 * 4]);
      else
        b4 = *reinterpret_cast<const float4*>(&xt[(t * NN + k0 + brow) * BB + (j0 - BB * HH) + bcol4 * 4]);
      *reinterpret_cast<float4*>(&Bs[brow][bcol4 * 4]) = b4;
    }
    __syncthreads();
#pragma unroll
    for (int kk = 0; kk < 32; ++kk) {
      float4 av = *reinterpret_cast<const float4*>(&As[kk][ty * 4]);
      float4 bv = *reinterpret_cast<const float4*>(&Bs[kk][tx * 4]);
      float a[4] = {av.x, av.y, av.z, av.w};
      float b[4] = {bv.x, bv.y, bv.z, bv.w};
#pragma unroll
      for (int i = 0; i < 4; ++i)
#pragma unroll
        for (int j = 0; j < 4; ++j) acc[i][j] += a[i] * b[j];
    }
    __syncthreads();
  }
  float* dst = azp + (size_t)kz * AZS;
#pragma unroll
  for (int i = 0; i < 4; ++i) {
    float4 v = {acc[i][0], acc[i][1], acc[i][2], acc[i][3]};
    *reinterpret_cast<float4*>(&dst[(n0 + ty * 4 + i) * COLS + j0 + tx * 4]) = v;
  }
}

__global__ __launch_bounds__(256) void k_step(const float* __restrict__ xt,
                                              const float* __restrict__ W,
                                              const float* __restrict__ bias,
                                              const float* __restrict__ azp,
                                              float* __restrict__ h,
                                              float* __restrict__ c,
                                              float* __restrict__ out,
                                              int t, int ks) {
  __shared__ float Wl[2 * CC * GG];
  __shared__ float zl[2 * CC * 68];
  int tid = threadIdx.x, n = blockIdx.x;
  const float4* Wg = reinterpret_cast<const float4*>(&W[n * (2 * CC * GG)]);
  for (int i = tid; i < (2 * CC * GG) / 4; i += 256)
    *reinterpret_cast<float4*>(&Wl[i * 4]) = Wg[i];
  for (int i = tid; i < BB * HH; i += 256) {
    int b = i >> 5, hh = i & 31;
    zl[(1 + hh) * 68 + b] = h[n * (BB * HH) + i];
    float s = azp[n * COLS + i];
    for (int kz = 1; kz < ks; ++kz) s += azp[(size_t)kz * AZS + n * COLS + i];
    zl[(CC + 1 + hh) * 68 + b] = s;
  }
  if (tid < BB) {
    zl[0 * 68 + tid] = xt[(t * NN + n) * BB + tid];
    float s = azp[n * COLS + BB * HH + tid];
    for (int kz = 1; kz < ks; ++kz) s += azp[(size_t)kz * AZS + n * COLS + BB * HH + tid];
    zl[CC * 68 + tid] = s;
  }
  __syncthreads();
  int tx = tid & 31, tyb = tid >> 5;
  float acc[8][4];
  {
    float4 bv = *reinterpret_cast<const float4*>(&bias[n * GG + tx * 4]);
#pragma unroll
    for (int bb = 0; bb < 8; ++bb) {
      acc[bb][0] = bv.x; acc[bb][1] = bv.y; acc[bb][2] = bv.z; acc[bb][3] = bv.w;
    }
  }
  for (int k = 0; k < 2; ++k) {
    for (int cc = 0; cc < CC; ++cc) {
      float4 w4 = *reinterpret_cast<const float4*>(&Wl[(k * CC + cc) * GG + tx * 4]);
      float4 za = *reinterpret_cast<const float4*>(&zl[(k * CC + cc) * 68 + tyb * 8]);
      float4 zb = *reinterpret_cast<const float4*>(&zl[(k * CC + cc) * 68 + tyb * 8 + 4]);
      float zv[8] = {za.x, za.y, za.z, za.w, zb.x, zb.y, zb.z, zb.w};
      float wv[4] = {w4.x, w4.y, w4.z, w4.w};
#pragma unroll
      for (int bb = 0; bb < 8; ++bb)
#pragma unroll
        for (int j = 0; j < 4; ++j) acc[bb][j] += zv[bb] * wv[j];
    }
  }
  __syncthreads();
  float* gl = Wl;
#pragma unroll
  for (int bb = 0; bb < 8; ++bb) {
    float4 v = {acc[bb][0], acc[bb][1], acc[bb][2], acc[bb][3]};
    *reinterpret_cast<float4*>(&gl[(tyb * 8 + bb) * GG + tx * 4]) = v;
  }
  __syncthreads();
  for (int i = tid; i < BB * HH; i += 256) {
    int b = i >> 5, hh = i & 31;
    float gi = gl[b * GG + hh];
    float gf = gl[b * GG + 32 + hh];
    float go = gl[b * GG + 64 + hh];
    float gg = gl[b * GG + 96 + hh];
    float cold = c[n * (BB * HH) + i];
    float si = 1.f / (1.f + expf(-gi));
    float sf = 1.f / (1.f + expf(-gf));
    float so = 1.f / (1.f + expf(-go));
    float cnew = sf * cold + si * tanhf(gg);
    float hnew = so * tanhf(cnew);
    c[n * (BB * HH) + i] = cnew;
    h[n * (BB * HH) + i] = hnew;
    out[((b * TT + t) * NN + n) * HH + hh] = hnew;
  }
}

// ---------------- persistent whole-recurrence kernel ----------------
// 512 blocks x 256 threads, 51.7 KB LDS. Cross-block data (h, azp) via sc1
// (agent-scope relaxed) accesses -> LLC-coherent; barrier = hierarchical flag.
__global__ __launch_bounds__(256, 2) void k_persist(
    const float* __restrict__ A, float* __restrict__ h,
    const float* __restrict__ xt, const float* __restrict__ ax,
    const float* __restrict__ W, const float* __restrict__ bias,
    float* __restrict__ c, float* __restrict__ azp, float* __restrict__ out,
    unsigned* __restrict__ bar) {
  __shared__ float smem[12936];  // Wl 8448 + zl 4488 ; phase A uses front 4224
  float* Wl = smem;
  float* zl = smem + 8448;
  float* As = smem;            // [32][68]
  float* Bs = smem + 2176;     // [32][64]
  const int tid = threadIdx.x;
  const int bid = blockIdx.x;
  const int n = bid;
  const int tx = tid & 15, ty = tid >> 4;
  const int arow = tid >> 2, akc = (tid & 3) * 4;
  const int bcol4 = tid & 15, brow0 = tid >> 4;
  const int txb = tid & 31, tyb = tid >> 5;
  const float* Wg = W + (size_t)n * (2 * CC * GG);
  unsigned ep = 1;

  for (int t = 0; t < TT; ++t) {
    // ---------- phase A ----------
#pragma unroll 1
    for (int jj = 0; jj < 2; ++jj) {
      int job = bid + jj * NB;
      int kz = job & 3;
      int rem = job >> 2;
      int jc = rem & 31, nr = rem >> 5;
      int j0 = jc * 64, n0 = nr * 64;
      int kbase = kz * 128;
      float acc[4][4] = {};
      for (int k0 = kbase; k0 < kbase + 128; k0 += 32) {
        float4 a0 = *reinterpret_cast<const float4*>(&A[(n0 + arow) * NN + k0 + akc]);
        float4 a1 = *reinterpret_cast<const float4*>(&A[(n0 + arow) * NN + k0 + 16 + akc]);
        float b0[4], b1[4];
#pragma unroll
        for (int q = 0; q < 4; ++q) {
          b0[q] = cload(&h[(k0 + brow0) * 2048 + j0 + bcol4 * 4 + q]);
          b1[q] = cload(&h[(k0 + brow0 + 16) * 2048 + j0 + bcol4 * 4 + q]);
        }
        As[(akc + 0) * 68 + arow] = a0.x;
        As[(akc + 1) * 68 + arow] = a0.y;
        As[(akc + 2) * 68 + arow] = a0.z;
        As[(akc + 3) * 68 + arow] = a0.w;
        As[(16 + akc + 0) * 68 + arow] = a1.x;
        As[(16 + akc + 1) * 68 + arow] = a1.y;
        As[(16 + akc + 2) * 68 + arow] = a1.z;
        As[(16 + akc + 3) * 68 + arow] = a1.w;
#pragma unroll
        for (int q = 0; q < 4; ++q) {
          Bs[brow0 * 64 + bcol4 * 4 + q] = b0[q];
          Bs[(brow0 + 16) * 64 + bcol4 * 4 + q] = b1[q];
        }
        __syncthreads();
#pragma unroll
        for (int kk = 0; kk < 32; ++kk) {
          float4 av = *reinterpret_cast<const float4*>(&As[kk * 68 + ty * 4]);
          float4 bv = *reinterpret_cast<const float4*>(&Bs[kk * 64 + tx * 4]);
          float a[4] = {av.x, av.y, av.z, av.w};
          float b[4] = {bv.x, bv.y, bv.z, bv.w};
#pragma unroll
          for (int i = 0; i < 4; ++i)
#pragma unroll
            for (int j = 0; j < 4; ++j) acc[i][j] += a[i] * b[j];
        }
        __syncthreads();
      }
      float* dst = azp + (size_t)kz * AZS;
#pragma unroll
      for (int i = 0; i < 4; ++i)
#pragma unroll
        for (int j = 0; j < 4; ++j)
          cstore(&dst[(size_t)(n0 + ty * 4 + i) * COLS + j0 + tx * 4 + j], acc[i][j]);
    }
    gbar(bar, ep, bid); ++ep;

    // ---------- phase B ----------
    for (int i = tid; i < 2 * CC * GG / 4; i += 256)
      *reinterpret_cast<float4*>(&Wl[i * 4]) =
          *reinterpret_cast<const float4*>(&Wg[i * 4]);
    for (int i = tid; i < BB * HH; i += 256) {
      int b = i >> 5, hh = i & 31;
      zl[(1 + hh) * 68 + b] = cload(&h[n * 2048 + i]);
      float s = cload(&azp[(size_t)n * COLS + i]);
#pragma unroll
      for (int kz = 1; kz < KS; ++kz)
        s += cload(&azp[(size_t)kz * AZS + (size_t)n * COLS + i]);
      zl[(CC + 1 + hh) * 68 + b] = s;
    }
    if (tid < BB) {
      zl[0 * 68 + tid] = xt[(t * NN + n) * BB + tid];
      zl[CC * 68 + tid] = ax[(size_t)(t * NN + n) * BB + tid];
    }
    __syncthreads();
    float acc2[8][4];
    {
      float4 bv = *reinterpret_cast<const float4*>(&bias[n * GG + txb * 4]);
#pragma unroll
      for (int b2 = 0; b2 < 8; ++b2) {
        acc2[b2][0] = bv.x; acc2[b2][1] = bv.y;
        acc2[b2][2] = bv.z; acc2[b2][3] = bv.w;
      }
    }
    for (int k = 0; k < 2; ++k) {
      for (int cc2 = 0; cc2 < CC; ++cc2) {
        float4 w4 = *reinterpret_cast<const float4*>(&Wl[(k * CC + cc2) * GG + txb * 4]);
        float4 za = *reinterpret_cast<const float4*>(&zl[(k * CC + cc2) * 68 + tyb * 8]);
        float4 zb = *reinterpret_cast<const float4*>(&zl[(k * CC + cc2) * 68 + tyb * 8 + 4]);
        float zv[8] = {za.x, za.y, za.z, za.w, zb.x, zb.y, zb.z, zb.w};
        float wv[4] = {w4.x, w4.y, w4.z, w4.w};
#pragma unroll
        for (int b2 = 0; b2 < 8; ++b2)
#pragma unroll
          for (int j2 = 0; j2 < 4; ++j2) acc2[b2][j2] += zv[b2] * wv[j2];
      }
    }
    __syncthreads();
    float* gl = Wl;
#pragma unroll
    for (int b2 = 0; b2 < 8; ++b2) {
      float4 v = {acc2[b2][0], acc2[b2][1], acc2[b2][2], acc2[b2][3]};
      *reinterpret_cast<float4*>(&gl[(tyb * 8 + b2) * GG + txb * 4]) = v;
    }
    __syncthreads();
    for (int i = tid; i < BB * HH; i += 256) {
      int b = i >> 5, hh = i & 31;
      float gi = gl[b * GG + hh];
      float gf = gl[b * GG + 32 + hh];
      float go = gl[b * GG + 64 + hh];
      float gg = gl[b * GG + 96 + hh];
      float cold = c[n * 2048 + i];
      float si = 1.f / (1.f + expf(-gi));
      float sf = 1.f / (1.f + expf(-gf));
      float so = 1.f / (1.f + expf(-go));
      float cnew = sf * cold + si * tanhf(gg);
      float hnew = so * tanhf(cnew);
      c[n * 2048 + i] = cnew;
      cstore(&h[n * 2048 + i], hnew);
      out[((size_t)(b * TT + t) * NN + n) * HH + hh] = hnew;
    }
    gbar(bar, ep, bid); ++ep;
  }
}

extern "C" void kernel_launch(void* const* d_in, const int* in_sizes, int n_in,
                              void* d_out, int out_size, void* d_ws, size_t ws_size,
                              hipStream_t stream) {
  const float* x    = (const float*)d_in[0];
  const float* init = (const float*)d_in[1];
  const float* E    = (const float*)d_in[2];
  const float* mask = (const float*)d_in[3];
  const float* Wp   = (const float*)d_in[4];
  const float* bp   = (const float*)d_in[5];
  float* out = (float*)d_out;
  float* ws = (float*)d_ws;
  float* A    = ws;
  float* W    = A + NN * NN;
  float* bias = W + NN * 2 * CC * GG;
  float* xt   = bias + NN * GG;
  float* ax   = xt + TT * NN * BB;
  float* h    = ax + TT * NN * BB;
  float* c    = h + NN * BB * HH;
  float* azp  = c + NN * BB * HH;
  unsigned* bar = (unsigned*)(azp + (size_t)KS * AZS);  // 128B-aligned by layout

  k_A<<<NN, 256, 0, stream>>>(E, mask, A);
  k_Wb<<<NN, 256, 0, stream>>>(E, Wp, bp, W, bias);
  k_xt<<<TT * 8, 256, 0, stream>>>(x, xt);
  k_ax<<<dim3(TT, 8), 256, 0, stream>>>(A, xt, ax);
  k_init<<<(NN * BB * HH + 255) / 256, 256, 0, stream>>>(init, h, c, bar);

  void* args[10] = {(void*)&A, (void*)&h, (void*)&xt, (void*)&ax, (void*)&W,
                    (void*)&bias, (void*)&c, (void*)&azp, (void*)&out, (void*)&bar};
  hipError_t err = hipLaunchCooperativeKernel((const void*)k_persist, dim3(NB),
                                              dim3(256), args, 0, stream);
  if (err != hipSuccess) {
    for (int t = 0; t < TT; ++t) {
      k_gemm<<<dim3(33, 8, KS), 256, 0, stream>>>(A, h, xt, azp, t, KS);
      k_step<<<NN, 256, 0, stream>>>(xt, W, bias, azp, h, c, out, t, KS);
    }
  }
}